// Round 11
// baseline (212.062 us; speedup 1.0000x reference)
//
#include <hip/hip_runtime.h>

// Problem constants (match reference)
#define S_LEN 4096
#define DMODEL 1024
#define NH 16
#define DH 64
#define WIN 256
#define NQKV 3072  // fused QKV output width

typedef __attribute__((ext_vector_type(8))) short short8;
typedef __attribute__((ext_vector_type(4))) short sh4;
typedef __attribute__((ext_vector_type(4))) float floatx4;

__device__ __forceinline__ ushort f2bf(float f) {
    union { float f; unsigned int i; } x;
    x.f = f;
    unsigned int r = x.i + 0x7FFFu + ((x.i >> 16) & 1u);  // RNE
    return (ushort)(r >> 16);
}

// ---------------------------------------------------------------------------
// Fused fp32 -> bf16 convert for x, wq, wk, wv, wo in ONE dispatch.
// (Fusing x-conversion into the GEMM measured −26us net, R9 — keep separate.)
// ---------------------------------------------------------------------------
__global__ __launch_bounds__(256) void cvt_all(const float* __restrict__ x,
                                               const float* __restrict__ wq,
                                               const float* __restrict__ wk,
                                               const float* __restrict__ wv,
                                               const float* __restrict__ wo,
                                               ushort* __restrict__ xb,
                                               ushort* __restrict__ W3b,
                                               ushort* __restrict__ wob,
                                               int nx8, int nw8) {
    int i = blockIdx.x * 256 + threadIdx.x;
    const float* src;
    ushort* dst;
    if (i < nx8) {
        src = x + (size_t)i * 8;            dst = xb + (size_t)i * 8;
    } else {
        int j = i - nx8;
        int which = j / nw8, r = j - which * nw8;
        if (which >= 4) return;
        const float* w4[4] = {wq, wk, wv, wo};
        src = w4[which] + (size_t)r * 8;
        dst = (which == 3 ? wob : W3b + (size_t)which * nw8 * 8) + (size_t)r * 8;
    }
    floatx4 f0 = *(const floatx4*)src;
    floatx4 f1 = *(const floatx4*)(src + 4);
    short8 v;
#pragma unroll
    for (int e = 0; e < 4; ++e) v[e] = (short)f2bf(f0[e]);
#pragma unroll
    for (int e = 0; e < 4; ++e) v[4 + e] = (short)f2bf(f1[e]);
    *(short8*)dst = v;
}

// ---------------------------------------------------------------------------
#define GLOAD16(src, dst)                                                     \
    __builtin_amdgcn_global_load_lds(                                         \
        (const __attribute__((address_space(1))) void*)(src),                 \
        (__attribute__((address_space(3))) void*)(dst), 16, 0, 0)

// ---------------------------------------------------------------------------
// 128x128 BK=64 single-buffer GEMM — FROZEN (R7/R8/R10 measured: QKV
// 53.0us/973TF, MfmaUtil 40%, 0 bank conflicts, FETCH 41MB). Both
// projections. Deep-pipeline ports (R1-R3), 128x256 (R4-R6), fused-cvt
// (R9): all measured slower. Do not touch.
// ---------------------------------------------------------------------------
template <bool OUTF32>
__global__ __launch_bounds__(256, 2) void gemm_t128(const ushort* __restrict__ A,
                                                    const ushort* __restrict__ W,
                                                    void* __restrict__ Cout,
                                                    int M, int N, int K) {
    __shared__ __align__(16) ushort As[128 * 64];  // 16 KB
    __shared__ __align__(16) ushort Ws[128 * 64];  // 16 KB

    const int tid = threadIdx.x;
    const int w = tid >> 6, l = tid & 63;

    // XCD-aware block swizzle (bijective when gridDim.y % 8 == 0).
    int bx, by;
    {
        const int nbx = gridDim.x, nby = gridDim.y;
        if ((nby & 7) == 0) {
            const int lin = blockIdx.y * nbx + blockIdx.x;
            const int rpb = nby >> 3;
            const int xcd = lin & 7, idx = lin >> 3;
            bx = idx / rpb;
            by = xcd * rpb + (idx - bx * rpb);
        } else {
            bx = blockIdx.x;
            by = blockIdx.y;
        }
    }
    const int bm0 = by * 128, bn0 = bx * 128;
    const int wm = (w >> 1) * 64, wn = (w & 1) * 64;
    const int lm = l & 15, quad = l >> 4;

    floatx4 acc[4][4] = {};

    // Staging: chunk c (16 B): row = c>>3, pos = c&7, global seg = pos^(row&7)
    int srow[4], scol[4];
#pragma unroll
    for (int p = 0; p < 4; ++p) {
        int c = p * 256 + tid;
        srow[p] = c >> 3;
        scol[p] = (((c & 7) ^ (srow[p] & 7))) * 8;
    }

    for (int k0 = 0; k0 < K; k0 += 64) {
#pragma unroll
        for (int p = 0; p < 4; ++p)
            GLOAD16(A + (size_t)(bm0 + srow[p]) * K + k0 + scol[p],
                    As + p * 2048 + tid * 8);
#pragma unroll
        for (int p = 0; p < 4; ++p)
            GLOAD16(W + (size_t)(bn0 + srow[p]) * K + k0 + scol[p],
                    Ws + p * 2048 + tid * 8);
        __syncthreads();  // drains vmcnt(0): staging complete

#pragma unroll
        for (int kk = 0; kk < 2; ++kk) {
            const int sseg = ((kk * 4 + quad) ^ (lm & 7)) * 8;
            short8 af[4], wf[4];
#pragma unroll
            for (int mi = 0; mi < 4; ++mi)
                af[mi] = *(const short8*)&As[(wm + mi * 16 + lm) * 64 + sseg];
#pragma unroll
            for (int ni = 0; ni < 4; ++ni)
                wf[ni] = *(const short8*)&Ws[(wn + ni * 16 + lm) * 64 + sseg];
#pragma unroll
            for (int mi = 0; mi < 4; ++mi)
#pragma unroll
                for (int ni = 0; ni < 4; ++ni)
                    acc[mi][ni] = __builtin_amdgcn_mfma_f32_16x16x32_bf16(
                        af[mi], wf[ni], acc[mi][ni], 0, 0, 0);
        }
        __syncthreads();  // frag reads done before next staging overwrites
    }

#pragma unroll
    for (int mi = 0; mi < 4; ++mi)
#pragma unroll
        for (int ni = 0; ni < 4; ++ni)
#pragma unroll
            for (int r = 0; r < 4; ++r) {
                int row = bm0 + wm + mi * 16 + quad * 4 + r;
                int col = bn0 + wn + ni * 16 + lm;
                if constexpr (OUTF32)
                    ((float*)Cout)[(size_t)row * N + col] = acc[mi][ni][r];
                else
                    ((ushort*)Cout)[(size_t)row * N + col] = f2bf(acc[mi][ni][r]);
            }
}

// ---------------------------------------------------------------------------
// MFMA sliding-window attention over fused QKV layout [M][3072].
// R11: staging chunk halved 128 -> 64 keys (6 chunks). LDS 36 -> ~19 KB
// per block, so 8 blocks/CU co-reside (32 waves/CU = FULL wave slots, vs
// 16 at R8-R10). The (c,g) loop enumerates the SAME 12 k0 values as before
// — identical per-wave compute, identical mask/softmax formulas; only the
// staging granularity changes. Same V-column permutation (32-key-group
// local), same Ks/Vt bank residue (144B stride == 272B mod 128, proven
// pattern), T14 reg-prefetch, XCD swizzle (R10, −2us), T5 setprio (R10).
// ---------------------------------------------------------------------------
#define KSP 72    // Ks row stride (shorts)
#define VTP 72    // Vt row stride (shorts) — 64 keys + 8 pad

__global__ __launch_bounds__(256) void swattn_mfma(const ushort* __restrict__ QKV,
                                                   ushort* __restrict__ O) {
    __shared__ __align__(16) ushort Ks[64 * KSP];  // 9216 B  [key][d]
    __shared__ __align__(16) ushort Vt[64 * VTP];  // 9216 B  [pi(d)][perm(key)]
    __shared__ __align__(16) float lW[128];        // 512 B

    // XCD-aware decode: consecutive post-swizzle ids (same XCD) = consecutive
    // jq within one (h,b) — K/V chunk overlap stays on one XCD's L2.
    int jq, h, b;
    {
        const int nbx = gridDim.x, nby = gridDim.y;
        const int nblk = nbx * nby * gridDim.z;
        int lin = blockIdx.x + nbx * (blockIdx.y + nby * blockIdx.z);
        if ((nblk & 7) == 0) {
            const int per = nblk >> 3;
            const int xcd = lin & 7, idx = lin >> 3;
            lin = xcd * per + idx;
        }
        jq = lin % nbx;
        h = (lin / nbx) % nby;
        b = lin / (nbx * nby);
    }
    const int tid = threadIdx.x;
    const int w = tid >> 6, l = tid & 63;
    const int quad = l >> 4, lc = l & 15;

    const int Q0 = jq * 128;  // block's query base

    const size_t base = (size_t)b * S_LEN * NQKV + (size_t)h * DH;
    const ushort* Qp = QKV + base;               // row stride NQKV
    const ushort* Kp = QKV + base + DMODEL;
    const ushort* Vp = QKV + base + 2 * DMODEL;

    short8 qf[2][2];
#pragma unroll
    for (int nq = 0; nq < 2; ++nq)
#pragma unroll
        for (int kk = 0; kk < 2; ++kk)
            qf[nq][kk] = *(const short8*)(Qp +
                (size_t)(Q0 + w * 32 + nq * 16 + lc) * NQKV + kk * 32 + quad * 8);

    floatx4 o[2][4] = {};
    float lsum[2] = {0.f, 0.f};

    const float sscale = 0.18033688011112042f;  // log2(e)/sqrt(64)
    const float M0 = 2.0f;                      // fixed shift (exact: shift-invariance)
    const int qlo = w * 32, qhi = w * 32 + 31;  // Q0-relative

    // Per-thread staging coordinates: 64-key chunk = 512 16B-chunks,
    // 2 per thread. key = (i*256+tid)>>3 in [0,64), seg = low 3 bits.
    int skey[2], sseg[2], svcol[2];
#pragma unroll
    for (int i = 0; i < 2; ++i) {
        int cc = i * 256 + tid;
        skey[i] = cc >> 3;
        sseg[i] = cc & 7;
        // V column permutation within each 32-key group (base k&32):
        // p5 = quad(k)*8 + kt(k)*4 + r(k) — matches the in-lane PV repack.
        int k = skey[i];
        svcol[i] = (k & 32) + ((k >> 2) & 3) * 8 + ((k >> 4) & 1) * 4 + (k & 3);
    }

    // Chunks c in [c0, 6): keys kg0 = Q0 - 256 + c*64 (>= 0 iff c >= c0)
    const int c0 = (Q0 >= 256) ? 0 : ((Q0 >= 128) ? 2 : 4);

    short8 kreg[2], vreg[2];
    {
        const int kg0 = Q0 - 256 + c0 * 64;
#pragma unroll
        for (int i = 0; i < 2; ++i) {
            kreg[i] = *(const short8*)(Kp + (size_t)(kg0 + skey[i]) * NQKV + sseg[i] * 8);
            vreg[i] = *(const short8*)(Vp + (size_t)(kg0 + skey[i]) * NQKV + sseg[i] * 8);
        }
    }

    for (int c = c0; c < 6; ++c) {
        __syncthreads();  // prev chunk's Ks/Vt reads done before overwrite
#pragma unroll
        for (int i = 0; i < 2; ++i) {
            *(short8*)&Ks[skey[i] * KSP + sseg[i] * 8] = kreg[i];
#pragma unroll
            for (int e = 0; e < 8; ++e)
                Vt[(e * 8 + sseg[i]) * VTP + svcol[i]] = (ushort)vreg[i][e];  // pi rows, perm cols
        }
        __syncthreads();

        if (c < 5) {  // T14: issue next chunk's loads; they land under compute
            const int kg0n = Q0 - 256 + (c + 1) * 64;
#pragma unroll
            for (int i = 0; i < 2; ++i) {
                kreg[i] = *(const short8*)(Kp + (size_t)(kg0n + skey[i]) * NQKV + sseg[i] * 8);
                vreg[i] = *(const short8*)(Vp + (size_t)(kg0n + skey[i]) * NQKV + sseg[i] * 8);
            }
        }

        const int krel0 = c * 64 - 256;
#pragma unroll
        for (int g = 0; g < 2; ++g) {
            const int k0 = krel0 + g * 32;
            if (k0 > qhi || k0 + 31 < qlo - 255) continue;

            floatx4 st[2][2];
            const floatx4 zero = {};
            __builtin_amdgcn_s_setprio(1);  // T5: favor MFMA wave
#pragma unroll
            for (int kt = 0; kt < 2; ++kt) {
                short8 kf0 = *(const short8*)&Ks[(g * 32 + kt * 16 + lc) * KSP + quad * 8];
                short8 kf1 = *(const short8*)&Ks[(g * 32 + kt * 16 + lc) * KSP + 32 + quad * 8];
#pragma unroll
                for (int nq = 0; nq < 2; ++nq) {
                    int kmin = k0 + kt * 16, qmin = qlo + nq * 16;
                    if (kmin > qmin + 15 || kmin + 270 < qmin) {  // fully masked
                        st[kt][nq] = zero;
                        continue;
                    }
                    st[kt][nq] = __builtin_amdgcn_mfma_f32_16x16x32_bf16(kf0, qf[nq][0], zero, 0, 0, 0);
                    st[kt][nq] = __builtin_amdgcn_mfma_f32_16x16x32_bf16(kf1, qf[nq][1], st[kt][nq], 0, 0, 0);
                }
            }
            __builtin_amdgcn_s_setprio(0);
            // Softmax transform IN PLACE (st becomes P in f32)
#pragma unroll
            for (int kt = 0; kt < 2; ++kt)
#pragma unroll
                for (int nq = 0; nq < 2; ++nq) {
                    int kmin = k0 + kt * 16, qmin = qlo + nq * 16;
                    if (kmin > qmin + 15 || kmin + 270 < qmin) {           // fully masked
                        st[kt][nq] = zero;
                    } else if (kmin + 15 <= qmin && kmin + 240 >= qmin) {  // interior: no mask
#pragma unroll
                        for (int r = 0; r < 4; ++r) {
                            float p = exp2f(st[kt][nq][r] * sscale - M0);
                            lsum[nq] += p;
                            st[kt][nq][r] = p;
                        }
                    } else {                                               // boundary
#pragma unroll
                        for (int r = 0; r < 4; ++r) {
                            int krel = kmin + quad * 4 + r;  // C row = key
                            int qrel = qmin + lc;            // C col = q
                            bool valid = (krel <= qrel) && (krel + 255 >= qrel);
                            float p = valid ? exp2f(st[kt][nq][r] * sscale - M0) : 0.f;
                            lsum[nq] += p;
                            st[kt][nq][r] = p;
                        }
                    }
                }

            short8 vf[4];
#pragma unroll
            for (int nd = 0; nd < 4; ++nd) {
                int prow = (lc & 7) * 8 + nd * 2 + (lc >> 3);  // pi(nd*16+lc)
                vf[nd] = *(const short8*)&Vt[prow * VTP + g * 32 + quad * 8];
            }
#pragma unroll
            for (int mq = 0; mq < 2; ++mq) {
                int qmin = qlo + mq * 16;
                if (k0 > qmin + 15 || k0 + 286 < qmin) continue;  // group fully masked
                union { unsigned int u[4]; short8 s; } pk;
                asm("v_cvt_pk_bf16_f32 %0, %1, %2"
                    : "=v"(pk.u[0]) : "v"(st[0][mq][0]), "v"(st[0][mq][1]));
                asm("v_cvt_pk_bf16_f32 %0, %1, %2"
                    : "=v"(pk.u[1]) : "v"(st[0][mq][2]), "v"(st[0][mq][3]));
                asm("v_cvt_pk_bf16_f32 %0, %1, %2"
                    : "=v"(pk.u[2]) : "v"(st[1][mq][0]), "v"(st[1][mq][1]));
                asm("v_cvt_pk_bf16_f32 %0, %1, %2"
                    : "=v"(pk.u[3]) : "v"(st[1][mq][2]), "v"(st[1][mq][3]));
                __builtin_amdgcn_s_setprio(1);  // T5
#pragma unroll
                for (int nd = 0; nd < 4; ++nd)
                    o[mq][nd] = __builtin_amdgcn_mfma_f32_16x16x32_bf16(pk.s, vf[nd], o[mq][nd], 0, 0, 0);
                __builtin_amdgcn_s_setprio(0);
            }
        }
    }

#pragma unroll
    for (int nq = 0; nq < 2; ++nq) {
        lsum[nq] += __shfl_xor(lsum[nq], 16);
        lsum[nq] += __shfl_xor(lsum[nq], 32);
    }
    if (l < 16) {
#pragma unroll
        for (int nq = 0; nq < 2; ++nq) lW[w * 32 + nq * 16 + l] = lsum[nq];
    }
    __threadfence_block();
#pragma unroll
    for (int mq = 0; mq < 2; ++mq) {
        floatx4 lv = *(const floatx4*)&lW[w * 32 + mq * 16 + quad * 4];
#pragma unroll
        for (int r = 0; r < 4; ++r) {
            float inv = 1.f / lv[r];
            int token = Q0 + w * 32 + mq * 16 + quad * 4 + r;
#pragma unroll
            for (int nd = 0; nd < 4; ++nd)
                O[(size_t)b * S_LEN * DMODEL + (size_t)token * DMODEL + h * DH + nd * 16 + lc] =
                    f2bf(o[mq][nd][r] * inv);
        }
    }
}

// ---------------------------------------------------------------------------
extern "C" void kernel_launch(void* const* d_in, const int* in_sizes, int n_in,
                              void* d_out, int out_size, void* d_ws, size_t ws_size,
                              hipStream_t stream) {
    const float* x  = (const float*)d_in[0];
    const float* wq = (const float*)d_in[1];
    const float* wk = (const float*)d_in[2];
    const float* wv = (const float*)d_in[3];
    const float* wo = (const float*)d_in[4];
    float* out = (float*)d_out;

    const int D = DMODEL;
    const int M = in_sizes[0] / D;  // B*S = 8192
    const int Bb = M / S_LEN;       // 2

    ushort* xb   = (ushort*)d_ws;
    ushort* W3b  = xb + (size_t)M * D;
    ushort* wob  = W3b + (size_t)NQKV * D;
    ushort* QKVb = wob + (size_t)D * D;
    ushort* Ob   = xb;  // overlay: xb dead after QKV GEMM

    const int nx8 = M * D / 8, nw8 = D * D / 8;
    const int ntot = nx8 + 4 * nw8;
    cvt_all<<<dim3((ntot + 255) / 256), dim3(256), 0, stream>>>(
        x, wq, wk, wv, wo, xb, W3b, wob, nx8, nw8);

    // Fused QKV projection: [M,3072] = xb @ W3b^T (frozen 128² structure)
    gemm_t128<false><<<dim3(NQKV / 128, M / 128), dim3(256), 0, stream>>>(
        xb, W3b, QKVb, M, NQKV, D);

    // Attention: 1024 blocks (128 queries each), 64-key chunks -> 8 blocks/CU
    swattn_mfma<<<dim3(S_LEN / 128, NH, Bb), dim3(256), 0, stream>>>(QKVb, Ob);

    // Output projection: out[M,1024] = Ob @ wob^T (fp32 out)
    gemm_t128<true><<<dim3(D / 128, M / 128), dim3(256), 0, stream>>>(
        Ob, wob, out, M, D, D);
}

// Round 12
// 203.134 us; speedup vs baseline: 1.0439x; 1.0439x over previous
//
#include <hip/hip_runtime.h>

// Problem constants (match reference)
#define S_LEN 4096
#define DMODEL 1024
#define NH 16
#define DH 64
#define WIN 256
#define NQKV 3072  // fused QKV output width

typedef __attribute__((ext_vector_type(8))) short short8;
typedef __attribute__((ext_vector_type(4))) short sh4;
typedef __attribute__((ext_vector_type(4))) float floatx4;

__device__ __forceinline__ ushort f2bf(float f) {
    union { float f; unsigned int i; } x;
    x.f = f;
    unsigned int r = x.i + 0x7FFFu + ((x.i >> 16) & 1u);  // RNE
    return (ushort)(r >> 16);
}

// ---------------------------------------------------------------------------
// Fused fp32 -> bf16 convert for x, wq, wk, wv, wo in ONE dispatch.
// (Fusing x-conversion into the GEMM measured −26us net, R9 — keep separate.)
// ---------------------------------------------------------------------------
__global__ __launch_bounds__(256) void cvt_all(const float* __restrict__ x,
                                               const float* __restrict__ wq,
                                               const float* __restrict__ wk,
                                               const float* __restrict__ wv,
                                               const float* __restrict__ wo,
                                               ushort* __restrict__ xb,
                                               ushort* __restrict__ W3b,
                                               ushort* __restrict__ wob,
                                               int nx8, int nw8) {
    int i = blockIdx.x * 256 + threadIdx.x;
    const float* src;
    ushort* dst;
    if (i < nx8) {
        src = x + (size_t)i * 8;            dst = xb + (size_t)i * 8;
    } else {
        int j = i - nx8;
        int which = j / nw8, r = j - which * nw8;
        if (which >= 4) return;
        const float* w4[4] = {wq, wk, wv, wo};
        src = w4[which] + (size_t)r * 8;
        dst = (which == 3 ? wob : W3b + (size_t)which * nw8 * 8) + (size_t)r * 8;
    }
    floatx4 f0 = *(const floatx4*)src;
    floatx4 f1 = *(const floatx4*)(src + 4);
    short8 v;
#pragma unroll
    for (int e = 0; e < 4; ++e) v[e] = (short)f2bf(f0[e]);
#pragma unroll
    for (int e = 0; e < 4; ++e) v[4 + e] = (short)f2bf(f1[e]);
    *(short8*)dst = v;
}

// ---------------------------------------------------------------------------
#define GLOAD16(src, dst)                                                     \
    __builtin_amdgcn_global_load_lds(                                         \
        (const __attribute__((address_space(1))) void*)(src),                 \
        (__attribute__((address_space(3))) void*)(dst), 16, 0, 0)

// ---------------------------------------------------------------------------
// 128x128 BK=64 single-buffer GEMM — FROZEN (R7/R8/R10 measured: QKV
// 53.0us/973TF, MfmaUtil 40%, 0 bank conflicts, FETCH 41MB). Both
// projections. Deep-pipeline ports (R1-R3), 128x256 (R4-R6), fused-cvt
// (R9): all measured slower. Do not touch.
// ---------------------------------------------------------------------------
template <bool OUTF32>
__global__ __launch_bounds__(256, 2) void gemm_t128(const ushort* __restrict__ A,
                                                    const ushort* __restrict__ W,
                                                    void* __restrict__ Cout,
                                                    int M, int N, int K) {
    __shared__ __align__(16) ushort As[128 * 64];  // 16 KB
    __shared__ __align__(16) ushort Ws[128 * 64];  // 16 KB

    const int tid = threadIdx.x;
    const int w = tid >> 6, l = tid & 63;

    // XCD-aware block swizzle (bijective when gridDim.y % 8 == 0).
    int bx, by;
    {
        const int nbx = gridDim.x, nby = gridDim.y;
        if ((nby & 7) == 0) {
            const int lin = blockIdx.y * nbx + blockIdx.x;
            const int rpb = nby >> 3;
            const int xcd = lin & 7, idx = lin >> 3;
            bx = idx / rpb;
            by = xcd * rpb + (idx - bx * rpb);
        } else {
            bx = blockIdx.x;
            by = blockIdx.y;
        }
    }
    const int bm0 = by * 128, bn0 = bx * 128;
    const int wm = (w >> 1) * 64, wn = (w & 1) * 64;
    const int lm = l & 15, quad = l >> 4;

    floatx4 acc[4][4] = {};

    // Staging: chunk c (16 B): row = c>>3, pos = c&7, global seg = pos^(row&7)
    int srow[4], scol[4];
#pragma unroll
    for (int p = 0; p < 4; ++p) {
        int c = p * 256 + tid;
        srow[p] = c >> 3;
        scol[p] = (((c & 7) ^ (srow[p] & 7))) * 8;
    }

    for (int k0 = 0; k0 < K; k0 += 64) {
#pragma unroll
        for (int p = 0; p < 4; ++p)
            GLOAD16(A + (size_t)(bm0 + srow[p]) * K + k0 + scol[p],
                    As + p * 2048 + tid * 8);
#pragma unroll
        for (int p = 0; p < 4; ++p)
            GLOAD16(W + (size_t)(bn0 + srow[p]) * K + k0 + scol[p],
                    Ws + p * 2048 + tid * 8);
        __syncthreads();  // drains vmcnt(0): staging complete

#pragma unroll
        for (int kk = 0; kk < 2; ++kk) {
            const int sseg = ((kk * 4 + quad) ^ (lm & 7)) * 8;
            short8 af[4], wf[4];
#pragma unroll
            for (int mi = 0; mi < 4; ++mi)
                af[mi] = *(const short8*)&As[(wm + mi * 16 + lm) * 64 + sseg];
#pragma unroll
            for (int ni = 0; ni < 4; ++ni)
                wf[ni] = *(const short8*)&Ws[(wn + ni * 16 + lm) * 64 + sseg];
#pragma unroll
            for (int mi = 0; mi < 4; ++mi)
#pragma unroll
                for (int ni = 0; ni < 4; ++ni)
                    acc[mi][ni] = __builtin_amdgcn_mfma_f32_16x16x32_bf16(
                        af[mi], wf[ni], acc[mi][ni], 0, 0, 0);
        }
        __syncthreads();  // frag reads done before next staging overwrites
    }

#pragma unroll
    for (int mi = 0; mi < 4; ++mi)
#pragma unroll
        for (int ni = 0; ni < 4; ++ni)
#pragma unroll
            for (int r = 0; r < 4; ++r) {
                int row = bm0 + wm + mi * 16 + quad * 4 + r;
                int col = bn0 + wn + ni * 16 + lm;
                if constexpr (OUTF32)
                    ((float*)Cout)[(size_t)row * N + col] = acc[mi][ni][r];
                else
                    ((ushort*)Cout)[(size_t)row * N + col] = f2bf(acc[mi][ni][r]);
            }
}

// ---------------------------------------------------------------------------
// MFMA sliding-window attention over fused QKV layout [M][3072].
// R12 = R10 exactly (best measured attn config; R11's 64-key chunks
// regressed +7us — barrier count doubled faster than occupancy paid;
// R4's K-direct and R7's 2-blocks/CU also measured worse):
//   QBLK=128 (4 blocks/CU), 128-key chunks, XCD-aware jq swizzle,
//   T5 setprio around MFMA clusters, Ps-free in-lane cvt_pk P repack,
//   V column permutation, K LDS-staged, T14 reg-prefetch.
// ---------------------------------------------------------------------------
#define KSP 72    // Ks row stride (shorts)
#define VTP 136   // Vt row stride (shorts)

__global__ __launch_bounds__(256) void swattn_mfma(const ushort* __restrict__ QKV,
                                                   ushort* __restrict__ O) {
    __shared__ __align__(16) ushort Ks[128 * KSP];  // 18432 B  [key][d]
    __shared__ __align__(16) ushort Vt[64 * VTP];   // 17408 B  [pi(d)][perm(key)]
    __shared__ __align__(16) float lW[128];         // 512 B

    // XCD-aware decode: consecutive post-swizzle ids (same XCD) = consecutive
    // jq within one (h,b) — K/V chunk overlap stays on one XCD's L2.
    int jq, h, b;
    {
        const int nbx = gridDim.x, nby = gridDim.y;
        const int nblk = nbx * nby * gridDim.z;
        int lin = blockIdx.x + nbx * (blockIdx.y + nby * blockIdx.z);
        if ((nblk & 7) == 0) {
            const int per = nblk >> 3;
            const int xcd = lin & 7, idx = lin >> 3;
            lin = xcd * per + idx;
        }
        jq = lin % nbx;
        h = (lin / nbx) % nby;
        b = lin / (nbx * nby);
    }
    const int tid = threadIdx.x;
    const int w = tid >> 6, l = tid & 63;
    const int quad = l >> 4, lc = l & 15;

    const int Q0 = jq * 128;  // block's query base

    const size_t base = (size_t)b * S_LEN * NQKV + (size_t)h * DH;
    const ushort* Qp = QKV + base;               // row stride NQKV
    const ushort* Kp = QKV + base + DMODEL;
    const ushort* Vp = QKV + base + 2 * DMODEL;

    short8 qf[2][2];
#pragma unroll
    for (int nq = 0; nq < 2; ++nq)
#pragma unroll
        for (int kk = 0; kk < 2; ++kk)
            qf[nq][kk] = *(const short8*)(Qp +
                (size_t)(Q0 + w * 32 + nq * 16 + lc) * NQKV + kk * 32 + quad * 8);

    floatx4 o[2][4] = {};
    float lsum[2] = {0.f, 0.f};

    const float sscale = 0.18033688011112042f;  // log2(e)/sqrt(64)
    const float M0 = 2.0f;                      // fixed shift (exact: shift-invariance)
    const int qlo = w * 32, qhi = w * 32 + 31;  // Q0-relative

    int skey[4], sseg[4], svcol[4];
#pragma unroll
    for (int i = 0; i < 4; ++i) {
        int cc = i * 256 + tid;
        skey[i] = cc >> 3;
        sseg[i] = cc & 7;
        int k = skey[i];
        svcol[i] = (k & 96) + ((k >> 2) & 3) * 8 + ((k >> 4) & 1) * 4 + (k & 3);
    }

    const int c0 = (Q0 >= 256) ? 0 : ((Q0 >= 128) ? 1 : 2);

    short8 kreg[4], vreg[4];
    {
        const int kg0 = Q0 - 256 + c0 * 128;
#pragma unroll
        for (int i = 0; i < 4; ++i) {
            kreg[i] = *(const short8*)(Kp + (size_t)(kg0 + skey[i]) * NQKV + sseg[i] * 8);
            vreg[i] = *(const short8*)(Vp + (size_t)(kg0 + skey[i]) * NQKV + sseg[i] * 8);
        }
    }

    for (int c = c0; c < 3; ++c) {
        __syncthreads();  // prev chunk's Ks/Vt reads done before overwrite
#pragma unroll
        for (int i = 0; i < 4; ++i) {
            *(short8*)&Ks[skey[i] * KSP + sseg[i] * 8] = kreg[i];
#pragma unroll
            for (int e = 0; e < 8; ++e)
                Vt[(e * 8 + sseg[i]) * VTP + svcol[i]] = (ushort)vreg[i][e];  // pi rows, perm cols
        }
        __syncthreads();

        if (c < 2) {  // T14: issue next chunk's loads; they land under compute
            const int kg0n = Q0 - 256 + (c + 1) * 128;
#pragma unroll
            for (int i = 0; i < 4; ++i) {
                kreg[i] = *(const short8*)(Kp + (size_t)(kg0n + skey[i]) * NQKV + sseg[i] * 8);
                vreg[i] = *(const short8*)(Vp + (size_t)(kg0n + skey[i]) * NQKV + sseg[i] * 8);
            }
        }

        const int krel0 = c * 128 - 256;
#pragma unroll
        for (int g = 0; g < 4; ++g) {
            const int k0 = krel0 + g * 32;
            if (k0 > qhi || k0 + 31 < qlo - 255) continue;

            floatx4 st[2][2];
            const floatx4 zero = {};
            __builtin_amdgcn_s_setprio(1);  // T5: favor MFMA wave
#pragma unroll
            for (int kt = 0; kt < 2; ++kt) {
                short8 kf0 = *(const short8*)&Ks[(g * 32 + kt * 16 + lc) * KSP + quad * 8];
                short8 kf1 = *(const short8*)&Ks[(g * 32 + kt * 16 + lc) * KSP + 32 + quad * 8];
#pragma unroll
                for (int nq = 0; nq < 2; ++nq) {
                    int kmin = k0 + kt * 16, qmin = qlo + nq * 16;
                    if (kmin > qmin + 15 || kmin + 270 < qmin) {  // fully masked
                        st[kt][nq] = zero;
                        continue;
                    }
                    st[kt][nq] = __builtin_amdgcn_mfma_f32_16x16x32_bf16(kf0, qf[nq][0], zero, 0, 0, 0);
                    st[kt][nq] = __builtin_amdgcn_mfma_f32_16x16x32_bf16(kf1, qf[nq][1], st[kt][nq], 0, 0, 0);
                }
            }
            __builtin_amdgcn_s_setprio(0);
            // Softmax transform IN PLACE (st becomes P in f32)
#pragma unroll
            for (int kt = 0; kt < 2; ++kt)
#pragma unroll
                for (int nq = 0; nq < 2; ++nq) {
                    int kmin = k0 + kt * 16, qmin = qlo + nq * 16;
                    if (kmin > qmin + 15 || kmin + 270 < qmin) {           // fully masked
                        st[kt][nq] = zero;
                    } else if (kmin + 15 <= qmin && kmin + 240 >= qmin) {  // interior: no mask
#pragma unroll
                        for (int r = 0; r < 4; ++r) {
                            float p = exp2f(st[kt][nq][r] * sscale - M0);
                            lsum[nq] += p;
                            st[kt][nq][r] = p;
                        }
                    } else {                                               // boundary
#pragma unroll
                        for (int r = 0; r < 4; ++r) {
                            int krel = kmin + quad * 4 + r;  // C row = key
                            int qrel = qmin + lc;            // C col = q
                            bool valid = (krel <= qrel) && (krel + 255 >= qrel);
                            float p = valid ? exp2f(st[kt][nq][r] * sscale - M0) : 0.f;
                            lsum[nq] += p;
                            st[kt][nq][r] = p;
                        }
                    }
                }

            short8 vf[4];
#pragma unroll
            for (int nd = 0; nd < 4; ++nd) {
                int prow = (lc & 7) * 8 + nd * 2 + (lc >> 3);  // pi(nd*16+lc)
                vf[nd] = *(const short8*)&Vt[prow * VTP + g * 32 + quad * 8];
            }
#pragma unroll
            for (int mq = 0; mq < 2; ++mq) {
                int qmin = qlo + mq * 16;
                if (k0 > qmin + 15 || k0 + 286 < qmin) continue;  // group fully masked
                union { unsigned int u[4]; short8 s; } pk;
                asm("v_cvt_pk_bf16_f32 %0, %1, %2"
                    : "=v"(pk.u[0]) : "v"(st[0][mq][0]), "v"(st[0][mq][1]));
                asm("v_cvt_pk_bf16_f32 %0, %1, %2"
                    : "=v"(pk.u[1]) : "v"(st[0][mq][2]), "v"(st[0][mq][3]));
                asm("v_cvt_pk_bf16_f32 %0, %1, %2"
                    : "=v"(pk.u[2]) : "v"(st[1][mq][0]), "v"(st[1][mq][1]));
                asm("v_cvt_pk_bf16_f32 %0, %1, %2"
                    : "=v"(pk.u[3]) : "v"(st[1][mq][2]), "v"(st[1][mq][3]));
                __builtin_amdgcn_s_setprio(1);  // T5
#pragma unroll
                for (int nd = 0; nd < 4; ++nd)
                    o[mq][nd] = __builtin_amdgcn_mfma_f32_16x16x32_bf16(pk.s, vf[nd], o[mq][nd], 0, 0, 0);
                __builtin_amdgcn_s_setprio(0);
            }
        }
    }

#pragma unroll
    for (int nq = 0; nq < 2; ++nq) {
        lsum[nq] += __shfl_xor(lsum[nq], 16);
        lsum[nq] += __shfl_xor(lsum[nq], 32);
    }
    if (l < 16) {
#pragma unroll
        for (int nq = 0; nq < 2; ++nq) lW[w * 32 + nq * 16 + l] = lsum[nq];
    }
    __threadfence_block();
#pragma unroll
    for (int mq = 0; mq < 2; ++mq) {
        floatx4 lv = *(const floatx4*)&lW[w * 32 + mq * 16 + quad * 4];
#pragma unroll
        for (int r = 0; r < 4; ++r) {
            float inv = 1.f / lv[r];
            int token = Q0 + w * 32 + mq * 16 + quad * 4 + r;
#pragma unroll
            for (int nd = 0; nd < 4; ++nd)
                O[(size_t)b * S_LEN * DMODEL + (size_t)token * DMODEL + h * DH + nd * 16 + lc] =
                    f2bf(o[mq][nd][r] * inv);
        }
    }
}

// ---------------------------------------------------------------------------
extern "C" void kernel_launch(void* const* d_in, const int* in_sizes, int n_in,
                              void* d_out, int out_size, void* d_ws, size_t ws_size,
                              hipStream_t stream) {
    const float* x  = (const float*)d_in[0];
    const float* wq = (const float*)d_in[1];
    const float* wk = (const float*)d_in[2];
    const float* wv = (const float*)d_in[3];
    const float* wo = (const float*)d_in[4];
    float* out = (float*)d_out;

    const int D = DMODEL;
    const int M = in_sizes[0] / D;  // B*S = 8192
    const int Bb = M / S_LEN;       // 2

    ushort* xb   = (ushort*)d_ws;
    ushort* W3b  = xb + (size_t)M * D;
    ushort* wob  = W3b + (size_t)NQKV * D;
    ushort* QKVb = wob + (size_t)D * D;
    ushort* Ob   = xb;  // overlay: xb dead after QKV GEMM

    const int nx8 = M * D / 8, nw8 = D * D / 8;
    const int ntot = nx8 + 4 * nw8;
    cvt_all<<<dim3((ntot + 255) / 256), dim3(256), 0, stream>>>(
        x, wq, wk, wv, wo, xb, W3b, wob, nx8, nw8);

    // Fused QKV projection: [M,3072] = xb @ W3b^T (frozen 128² structure)
    gemm_t128<false><<<dim3(NQKV / 128, M / 128), dim3(256), 0, stream>>>(
        xb, W3b, QKVb, M, NQKV, D);

    // Attention: 1024 blocks (128 queries each), XCD-swizzled jq order
    swattn_mfma<<<dim3(S_LEN / 128, NH, Bb), dim3(256), 0, stream>>>(QKVb, Ob);

    // Output projection: out[M,1024] = Ob @ wob^T (fp32 out)
    gemm_t128<true><<<dim3(D / 128, M / 128), dim3(256), 0, stream>>>(
        Ob, wob, out, M, D, D);
}